// Round 1
// baseline (4501.941 us; speedup 1.0000x reference)
//
#include <hip/hip_runtime.h>

// Problem constants (from reference)
constexpr int N_NODES = 50000;
constexpr int N_EDGES = 600000;
constexpr int ND = 128;   // NODE_DIM
constexpr int ED = 64;    // EDGE_DIM
constexpr int MD = 128;   // MSG_DIM
constexpr int H1 = 32;    // edge MLP hidden
constexpr int H2 = 64;    // node MLP hidden

// out = node_features (copy, float4-vectorized); atomics accumulate on top.
__global__ __launch_bounds__(256) void copy_nodes(const float* __restrict__ nf,
                                                  float* __restrict__ out) {
    int i = blockIdx.x * 256 + threadIdx.x;
    constexpr int total = N_NODES * ND / 4;
    if (i < total) {
        reinterpret_cast<float4*>(out)[i] = reinterpret_cast<const float4*>(nf)[i];
    }
}

// One thread per edge: fused 4-layer MLP + atomic scatter-add.
// h[32], h2[64] live in VGPRs; edge_msg is computed on the fly in layer 3.
// All weight indices are wave-uniform -> scalar loads (s_load) feeding v_fmac.
__global__ __launch_bounds__(256, 2) void mpn_edge(
    const float* __restrict__ nf, const float* __restrict__ ef,
    const int* __restrict__ eidx,
    const float* __restrict__ We1, const float* __restrict__ be1,
    const float* __restrict__ We2, const float* __restrict__ be2,
    const float* __restrict__ Wn1, const float* __restrict__ bn1,
    const float* __restrict__ Wn2, const float* __restrict__ bn2,
    float* __restrict__ out)
{
    const int e = blockIdx.x * 256 + threadIdx.x;
    if (e >= N_EDGES) return;
    const int src = eidx[e];
    const int dst = eidx[N_EDGES + e];

    const float4* __restrict__ srcf = reinterpret_cast<const float4*>(nf) + src * (ND / 4);
    const float4* __restrict__ dstf = reinterpret_cast<const float4*>(nf) + dst * (ND / 4);
    const float4* __restrict__ egf  = reinterpret_cast<const float4*>(ef) + e * (ED / 4);

    // ---------------- layer 1: h = relu([src_f|dst_f|edge_f] @ We1 + be1) ----
    float h[H1];
    #pragma unroll
    for (int j = 0; j < H1; ++j) h[j] = be1[j];

    #pragma unroll 2
    for (int k4 = 0; k4 < ND / 4; ++k4) {            // rows 0..127: src_f
        float4 v = srcf[k4];
        float xs[4] = {v.x, v.y, v.z, v.w};
        #pragma unroll
        for (int c = 0; c < 4; ++c) {
            const float* w = We1 + (k4 * 4 + c) * H1;
            #pragma unroll
            for (int j = 0; j < H1; ++j) h[j] = fmaf(xs[c], w[j], h[j]);
        }
    }
    #pragma unroll 2
    for (int k4 = 0; k4 < ND / 4; ++k4) {            // rows 128..255: dst_f
        float4 v = dstf[k4];
        float xs[4] = {v.x, v.y, v.z, v.w};
        #pragma unroll
        for (int c = 0; c < 4; ++c) {
            const float* w = We1 + (ND + k4 * 4 + c) * H1;
            #pragma unroll
            for (int j = 0; j < H1; ++j) h[j] = fmaf(xs[c], w[j], h[j]);
        }
    }
    #pragma unroll 2
    for (int k4 = 0; k4 < ED / 4; ++k4) {            // rows 256..319: edge_f
        float4 v = egf[k4];
        float xs[4] = {v.x, v.y, v.z, v.w};
        #pragma unroll
        for (int c = 0; c < 4; ++c) {
            const float* w = We1 + (2 * ND + k4 * 4 + c) * H1;
            #pragma unroll
            for (int j = 0; j < H1; ++j) h[j] = fmaf(xs[c], w[j], h[j]);
        }
    }
    #pragma unroll
    for (int j = 0; j < H1; ++j) h[j] = fmaxf(h[j], 0.0f);

    // ---------------- layer 3: h2 = relu([dst_f|edge_msg] @ Wn1 + bn1) -------
    // (edge_msg[k] = relu(h . We2[:,k] + be2[k]) computed inline -> layer 2 fused)
    float h2[H2];
    #pragma unroll
    for (int j = 0; j < H2; ++j) h2[j] = bn1[j];

    #pragma unroll 1
    for (int k4 = 0; k4 < ND / 4; ++k4) {            // rows 0..127: dst_f
        float4 v = dstf[k4];
        float xs[4] = {v.x, v.y, v.z, v.w};
        #pragma unroll
        for (int c = 0; c < 4; ++c) {
            const float* w = Wn1 + (k4 * 4 + c) * H2;
            #pragma unroll
            for (int j = 0; j < H2; ++j) h2[j] = fmaf(xs[c], w[j], h2[j]);
        }
    }
    #pragma unroll 1
    for (int k = 0; k < MD; ++k) {                   // rows 128..255: edge_msg
        float m = be2[k];
        #pragma unroll
        for (int t = 0; t < H1; ++t) m = fmaf(h[t], We2[t * MD + k], m);
        m = fmaxf(m, 0.0f);
        const float* w = Wn1 + (ND + k) * H2;
        #pragma unroll
        for (int j = 0; j < H2; ++j) h2[j] = fmaf(m, w[j], h2[j]);
    }
    #pragma unroll
    for (int j = 0; j < H2; ++j) h2[j] = fmaxf(h2[j], 0.0f);

    // ---------------- layer 4 + scatter: out[dst] += relu(h2 @ Wn2 + bn2) ----
    float* orow = out + (size_t)dst * MD;
    #pragma unroll 1
    for (int jo = 0; jo < MD; ++jo) {
        float m = bn2[jo];
        #pragma unroll
        for (int t = 0; t < H2; ++t) m = fmaf(h2[t], Wn2[t * MD + jo], m);
        m = fmaxf(m, 0.0f);
        unsafeAtomicAdd(orow + jo, m);               // HW global_atomic_add_f32
    }
}

extern "C" void kernel_launch(void* const* d_in, const int* in_sizes, int n_in,
                              void* d_out, int out_size, void* d_ws, size_t ws_size,
                              hipStream_t stream) {
    const float* nf  = (const float*)d_in[0];
    const float* ef  = (const float*)d_in[1];
    const int*  eidx = (const int*)d_in[2];
    const float* We1 = (const float*)d_in[3];
    const float* be1 = (const float*)d_in[4];
    const float* We2 = (const float*)d_in[5];
    const float* be2 = (const float*)d_in[6];
    const float* Wn1 = (const float*)d_in[7];
    const float* bn1 = (const float*)d_in[8];
    const float* Wn2 = (const float*)d_in[9];
    const float* bn2 = (const float*)d_in[10];
    float* out = (float*)d_out;

    // 1) out = node_features
    constexpr int copy_elems = N_NODES * ND / 4;
    copy_nodes<<<(copy_elems + 255) / 256, 256, 0, stream>>>(nf, out);

    // 2) fused edge MLP + atomic scatter
    mpn_edge<<<(N_EDGES + 255) / 256, 256, 0, stream>>>(
        nf, ef, eidx, We1, be1, We2, be2, Wn1, bn1, Wn2, bn2, out);
}

// Round 2
// 1228.565 us; speedup vs baseline: 3.6644x; 3.6644x over previous
//
#include <hip/hip_runtime.h>
#include <hip/hip_bf16.h>

// Problem constants (from reference)
constexpr int N_NODES = 50000;
constexpr int N_EDGES = 600000;
constexpr int ND = 128;   // NODE_DIM
constexpr int ED = 64;    // EDGE_DIM
constexpr int MD = 128;   // MSG_DIM
constexpr int H1 = 32;    // edge MLP hidden
constexpr int H2 = 64;    // node MLP hidden

// ---------------- workspace layout (bytes) ----------------
// msgs   : N_EDGES * MD * 2 (bf16)        = 153,600,000
// perm   : N_EDGES * 4                    =   2,400,000
// counts : N_NODES * 4                    =     200,000
// offsets: (N_NODES+1) * 4                =     200,004
// cursor : N_NODES * 4                    =     200,000
constexpr size_t WS_MSGS    = 0;
constexpr size_t WS_PERM    = WS_MSGS + (size_t)N_EDGES * MD * 2;
constexpr size_t WS_COUNTS  = WS_PERM + (size_t)N_EDGES * 4;
constexpr size_t WS_OFFSETS = WS_COUNTS + (size_t)N_NODES * 4;
constexpr size_t WS_CURSOR  = WS_OFFSETS + (size_t)(N_NODES + 1) * 4;
constexpr size_t WS_NEEDED  = WS_CURSOR + (size_t)N_NODES * 4;

__device__ inline unsigned pack2bf(float a, float b) {
    __hip_bfloat162 p;
    p.x = __float2bfloat16(a);
    p.y = __float2bfloat16(b);
    return *reinterpret_cast<unsigned*>(&p);
}

// ---------------- CSR build ----------------
__global__ __launch_bounds__(256) void hist_kernel(const int* __restrict__ eidx,
                                                   int* __restrict__ counts) {
    int e = blockIdx.x * 256 + threadIdx.x;
    if (e < N_EDGES) atomicAdd(&counts[eidx[N_EDGES + e]], 1);
}

// single-block exclusive scan over 50000 counts -> offsets[50001], cursor copy
__global__ __launch_bounds__(1024) void scan_kernel(const int* __restrict__ counts,
                                                    int* __restrict__ offsets,
                                                    int* __restrict__ cursor) {
    constexpr int T = 1024;
    constexpr int CHUNK = (N_NODES + T - 1) / T;  // 49
    const int tid = threadIdx.x;
    const int base = tid * CHUNK;

    int s = 0;
    #pragma unroll
    for (int i = 0; i < CHUNK; ++i) {
        int idx = base + i;
        if (idx < N_NODES) s += counts[idx];
    }
    __shared__ int sm[T];
    sm[tid] = s;
    __syncthreads();
    // Hillis-Steele inclusive scan
    for (int off = 1; off < T; off <<= 1) {
        int v = (tid >= off) ? sm[tid - off] : 0;
        __syncthreads();
        sm[tid] += v;
        __syncthreads();
    }
    int run = sm[tid] - s;  // exclusive prefix of this chunk
    #pragma unroll
    for (int i = 0; i < CHUNK; ++i) {
        int idx = base + i;
        if (idx < N_NODES) {
            offsets[idx] = run;
            cursor[idx] = run;
            run += counts[idx];
        }
    }
    if (tid == T - 1) offsets[N_NODES] = sm[T - 1];
}

__global__ __launch_bounds__(256) void fill_kernel(const int* __restrict__ eidx,
                                                   int* __restrict__ cursor,
                                                   int* __restrict__ perm) {
    int e = blockIdx.x * 256 + threadIdx.x;
    if (e < N_EDGES) {
        int pos = atomicAdd(&cursor[eidx[N_EDGES + e]], 1);
        perm[pos] = e;
    }
}

// ---------------- Phase A: fused per-edge 4-layer MLP -> bf16 msg rows ------
__global__ __launch_bounds__(256, 2) void edge_mlp(
    const float* __restrict__ nf, const float* __restrict__ ef,
    const int* __restrict__ eidx,
    const float* __restrict__ We1, const float* __restrict__ be1,
    const float* __restrict__ We2, const float* __restrict__ be2,
    const float* __restrict__ Wn1, const float* __restrict__ bn1,
    const float* __restrict__ Wn2, const float* __restrict__ bn2,
    unsigned* __restrict__ msgs)   // packed bf16x2, 64 uints per edge
{
    const int e = blockIdx.x * 256 + threadIdx.x;
    if (e >= N_EDGES) return;
    const int src = eidx[e];
    const int dst = eidx[N_EDGES + e];

    const float4* __restrict__ srcf = reinterpret_cast<const float4*>(nf) + src * (ND / 4);
    const float4* __restrict__ dstf = reinterpret_cast<const float4*>(nf) + dst * (ND / 4);
    const float4* __restrict__ egf  = reinterpret_cast<const float4*>(ef) + e * (ED / 4);

    // layer 1: h = relu([src_f|dst_f|edge_f] @ We1 + be1)
    float h[H1];
    #pragma unroll
    for (int j = 0; j < H1; ++j) h[j] = be1[j];

    #pragma unroll 2
    for (int k4 = 0; k4 < ND / 4; ++k4) {
        float4 v = srcf[k4];
        float xs[4] = {v.x, v.y, v.z, v.w};
        #pragma unroll
        for (int c = 0; c < 4; ++c) {
            const float* w = We1 + (k4 * 4 + c) * H1;
            #pragma unroll
            for (int j = 0; j < H1; ++j) h[j] = fmaf(xs[c], w[j], h[j]);
        }
    }
    #pragma unroll 2
    for (int k4 = 0; k4 < ND / 4; ++k4) {
        float4 v = dstf[k4];
        float xs[4] = {v.x, v.y, v.z, v.w};
        #pragma unroll
        for (int c = 0; c < 4; ++c) {
            const float* w = We1 + (ND + k4 * 4 + c) * H1;
            #pragma unroll
            for (int j = 0; j < H1; ++j) h[j] = fmaf(xs[c], w[j], h[j]);
        }
    }
    #pragma unroll 2
    for (int k4 = 0; k4 < ED / 4; ++k4) {
        float4 v = egf[k4];
        float xs[4] = {v.x, v.y, v.z, v.w};
        #pragma unroll
        for (int c = 0; c < 4; ++c) {
            const float* w = We1 + (2 * ND + k4 * 4 + c) * H1;
            #pragma unroll
            for (int j = 0; j < H1; ++j) h[j] = fmaf(xs[c], w[j], h[j]);
        }
    }
    #pragma unroll
    for (int j = 0; j < H1; ++j) h[j] = fmaxf(h[j], 0.0f);

    // layer 3: h2 = relu([dst_f|edge_msg] @ Wn1 + bn1), layer 2 fused inline
    float h2[H2];
    #pragma unroll
    for (int j = 0; j < H2; ++j) h2[j] = bn1[j];

    #pragma unroll 1
    for (int k4 = 0; k4 < ND / 4; ++k4) {
        float4 v = dstf[k4];
        float xs[4] = {v.x, v.y, v.z, v.w};
        #pragma unroll
        for (int c = 0; c < 4; ++c) {
            const float* w = Wn1 + (k4 * 4 + c) * H2;
            #pragma unroll
            for (int j = 0; j < H2; ++j) h2[j] = fmaf(xs[c], w[j], h2[j]);
        }
    }
    #pragma unroll 1
    for (int k = 0; k < MD; ++k) {
        float m = be2[k];
        #pragma unroll
        for (int t = 0; t < H1; ++t) m = fmaf(h[t], We2[t * MD + k], m);
        m = fmaxf(m, 0.0f);
        const float* w = Wn1 + (ND + k) * H2;
        #pragma unroll
        for (int j = 0; j < H2; ++j) h2[j] = fmaf(m, w[j], h2[j]);
    }
    #pragma unroll
    for (int j = 0; j < H2; ++j) h2[j] = fmaxf(h2[j], 0.0f);

    // layer 4: msg = relu(h2 @ Wn2 + bn2), packed bf16 -> ws (coalesced 16B)
    uint4* mrow = reinterpret_cast<uint4*>(msgs) + (size_t)e * (MD / 8);
    #pragma unroll 1
    for (int jo0 = 0; jo0 < MD; jo0 += 8) {
        float m[8];
        #pragma unroll
        for (int i = 0; i < 8; ++i) m[i] = bn2[jo0 + i];
        #pragma unroll
        for (int t = 0; t < H2; ++t) {
            const float hv = h2[t];
            const float* w = Wn2 + t * MD + jo0;
            #pragma unroll
            for (int i = 0; i < 8; ++i) m[i] = fmaf(hv, w[i], m[i]);
        }
        #pragma unroll
        for (int i = 0; i < 8; ++i) m[i] = fmaxf(m[i], 0.0f);
        uint4 p;
        p.x = pack2bf(m[0], m[1]);
        p.y = pack2bf(m[2], m[3]);
        p.z = pack2bf(m[4], m[5]);
        p.w = pack2bf(m[6], m[7]);
        mrow[jo0 / 8] = p;
    }
}

// ---------------- Phase B: per-node gather-sum ------------------------------
// one wave (64 lanes) per node; lane handles features [2j, 2j+1]
__global__ __launch_bounds__(256) void gather_kernel(
    const float* __restrict__ nf,
    const unsigned* __restrict__ msgs,
    const int* __restrict__ offsets,
    const int* __restrict__ perm,
    float* __restrict__ out)
{
    const int node = blockIdx.x * 4 + (threadIdx.x >> 6);
    const int lane = threadIdx.x & 63;

    float2 a = reinterpret_cast<const float2*>(nf)[node * (ND / 2) + lane];
    const int beg = offsets[node];
    const int end = offsets[node + 1];
    for (int i = beg; i < end; ++i) {
        const int e = perm[i];
        unsigned u = msgs[(size_t)e * (MD / 2) + lane];
        a.x += __uint_as_float(u << 16);
        a.y += __uint_as_float(u & 0xffff0000u);
    }
    reinterpret_cast<float2*>(out)[node * (ND / 2) + lane] = a;
}

// ---------------- fallback (atomic path) if ws is too small -----------------
__global__ __launch_bounds__(256) void copy_nodes(const float* __restrict__ nf,
                                                  float* __restrict__ out) {
    int i = blockIdx.x * 256 + threadIdx.x;
    constexpr int total = N_NODES * ND / 4;
    if (i < total)
        reinterpret_cast<float4*>(out)[i] = reinterpret_cast<const float4*>(nf)[i];
}

__global__ __launch_bounds__(256, 2) void mpn_edge_atomic(
    const float* __restrict__ nf, const float* __restrict__ ef,
    const int* __restrict__ eidx,
    const float* __restrict__ We1, const float* __restrict__ be1,
    const float* __restrict__ We2, const float* __restrict__ be2,
    const float* __restrict__ Wn1, const float* __restrict__ bn1,
    const float* __restrict__ Wn2, const float* __restrict__ bn2,
    float* __restrict__ out)
{
    const int e = blockIdx.x * 256 + threadIdx.x;
    if (e >= N_EDGES) return;
    const int src = eidx[e];
    const int dst = eidx[N_EDGES + e];
    const float4* srcf = reinterpret_cast<const float4*>(nf) + src * (ND / 4);
    const float4* dstf = reinterpret_cast<const float4*>(nf) + dst * (ND / 4);
    const float4* egf  = reinterpret_cast<const float4*>(ef) + e * (ED / 4);

    float h[H1];
    #pragma unroll
    for (int j = 0; j < H1; ++j) h[j] = be1[j];
    for (int k4 = 0; k4 < ND / 4; ++k4) {
        float4 v = srcf[k4]; float xs[4] = {v.x, v.y, v.z, v.w};
        for (int c = 0; c < 4; ++c) {
            const float* w = We1 + (k4 * 4 + c) * H1;
            for (int j = 0; j < H1; ++j) h[j] = fmaf(xs[c], w[j], h[j]);
        }
    }
    for (int k4 = 0; k4 < ND / 4; ++k4) {
        float4 v = dstf[k4]; float xs[4] = {v.x, v.y, v.z, v.w};
        for (int c = 0; c < 4; ++c) {
            const float* w = We1 + (ND + k4 * 4 + c) * H1;
            for (int j = 0; j < H1; ++j) h[j] = fmaf(xs[c], w[j], h[j]);
        }
    }
    for (int k4 = 0; k4 < ED / 4; ++k4) {
        float4 v = egf[k4]; float xs[4] = {v.x, v.y, v.z, v.w};
        for (int c = 0; c < 4; ++c) {
            const float* w = We1 + (2 * ND + k4 * 4 + c) * H1;
            for (int j = 0; j < H1; ++j) h[j] = fmaf(xs[c], w[j], h[j]);
        }
    }
    for (int j = 0; j < H1; ++j) h[j] = fmaxf(h[j], 0.0f);

    float h2[H2];
    for (int j = 0; j < H2; ++j) h2[j] = bn1[j];
    for (int k4 = 0; k4 < ND / 4; ++k4) {
        float4 v = dstf[k4]; float xs[4] = {v.x, v.y, v.z, v.w};
        for (int c = 0; c < 4; ++c) {
            const float* w = Wn1 + (k4 * 4 + c) * H2;
            for (int j = 0; j < H2; ++j) h2[j] = fmaf(xs[c], w[j], h2[j]);
        }
    }
    for (int k = 0; k < MD; ++k) {
        float m = be2[k];
        for (int t = 0; t < H1; ++t) m = fmaf(h[t], We2[t * MD + k], m);
        m = fmaxf(m, 0.0f);
        const float* w = Wn1 + (ND + k) * H2;
        for (int j = 0; j < H2; ++j) h2[j] = fmaf(m, w[j], h2[j]);
    }
    for (int j = 0; j < H2; ++j) h2[j] = fmaxf(h2[j], 0.0f);

    float* orow = out + (size_t)dst * MD;
    for (int jo = 0; jo < MD; ++jo) {
        float m = bn2[jo];
        for (int t = 0; t < H2; ++t) m = fmaf(h2[t], Wn2[t * MD + jo], m);
        m = fmaxf(m, 0.0f);
        unsafeAtomicAdd(orow + jo, m);
    }
}

extern "C" void kernel_launch(void* const* d_in, const int* in_sizes, int n_in,
                              void* d_out, int out_size, void* d_ws, size_t ws_size,
                              hipStream_t stream) {
    const float* nf  = (const float*)d_in[0];
    const float* ef  = (const float*)d_in[1];
    const int*  eidx = (const int*)d_in[2];
    const float* We1 = (const float*)d_in[3];
    const float* be1 = (const float*)d_in[4];
    const float* We2 = (const float*)d_in[5];
    const float* be2 = (const float*)d_in[6];
    const float* Wn1 = (const float*)d_in[7];
    const float* bn1 = (const float*)d_in[8];
    const float* Wn2 = (const float*)d_in[9];
    const float* bn2 = (const float*)d_in[10];
    float* out = (float*)d_out;

    if (ws_size < WS_NEEDED) {
        // fallback: atomic path (round-1 behavior)
        constexpr int copy_elems = N_NODES * ND / 4;
        copy_nodes<<<(copy_elems + 255) / 256, 256, 0, stream>>>(nf, out);
        mpn_edge_atomic<<<(N_EDGES + 255) / 256, 256, 0, stream>>>(
            nf, ef, eidx, We1, be1, We2, be2, Wn1, bn1, Wn2, bn2, out);
        return;
    }

    char* ws = (char*)d_ws;
    unsigned* msgs = (unsigned*)(ws + WS_MSGS);
    int* perm      = (int*)(ws + WS_PERM);
    int* counts    = (int*)(ws + WS_COUNTS);
    int* offsets   = (int*)(ws + WS_OFFSETS);
    int* cursor    = (int*)(ws + WS_CURSOR);

    // CSR build
    hipMemsetAsync(counts, 0, (size_t)N_NODES * 4, stream);
    hist_kernel<<<(N_EDGES + 255) / 256, 256, 0, stream>>>(eidx, counts);
    scan_kernel<<<1, 1024, 0, stream>>>(counts, offsets, cursor);
    fill_kernel<<<(N_EDGES + 255) / 256, 256, 0, stream>>>(eidx, cursor, perm);

    // Phase A: per-edge MLP -> bf16 msg rows
    edge_mlp<<<(N_EDGES + 255) / 256, 256, 0, stream>>>(
        nf, ef, eidx, We1, be1, We2, be2, Wn1, bn1, Wn2, bn2, msgs);

    // Phase B: per-node gather-sum
    gather_kernel<<<N_NODES / 4, 256, 0, stream>>>(nf, msgs, offsets, perm, out);
}

// Round 3
// 1208.946 us; speedup vs baseline: 3.7239x; 1.0162x over previous
//
#include <hip/hip_runtime.h>
#include <hip/hip_bf16.h>

// Problem constants (from reference)
constexpr int N_NODES = 50000;
constexpr int N_EDGES = 600000;
constexpr int ND = 128;   // NODE_DIM
constexpr int ED = 64;    // EDGE_DIM
constexpr int MD = 128;   // MSG_DIM
constexpr int H1 = 32;    // edge MLP hidden
constexpr int H2 = 64;    // node MLP hidden

// ---------------- workspace layout (bytes) ----------------
// msgs (CSR-ordered bf16 rows): N_EDGES * MD * 2 = 153,600,000
// slot   : N_EDGES * 4
// pre    : N_NODES * 128 * 2 (bf16: a1[32] | a2[32] | a3[64])
// counts / offsets / cursor : small
constexpr size_t WS_MSGS    = 0;
constexpr size_t WS_SLOT    = WS_MSGS + (size_t)N_EDGES * MD * 2;
constexpr size_t WS_PRE     = WS_SLOT + (size_t)N_EDGES * 4;
constexpr size_t WS_COUNTS  = WS_PRE + (size_t)N_NODES * 128 * 2;
constexpr size_t WS_OFFSETS = WS_COUNTS + (size_t)N_NODES * 4;
constexpr size_t WS_CURSOR  = WS_OFFSETS + (size_t)(N_NODES + 1) * 4;
constexpr size_t WS_NEEDED  = WS_CURSOR + (size_t)N_NODES * 4;

__device__ inline float bflo(unsigned u) { return __uint_as_float(u << 16); }
__device__ inline float bfhi(unsigned u) { return __uint_as_float(u & 0xffff0000u); }
__device__ inline unsigned pack2bf(float a, float b) {
    __hip_bfloat162 p;
    p.x = __float2bfloat16(a);
    p.y = __float2bfloat16(b);
    return *reinterpret_cast<unsigned*>(&p);
}

// ---------------- CSR build ----------------
__global__ __launch_bounds__(256) void hist_kernel(const int* __restrict__ eidx,
                                                   int* __restrict__ counts) {
    int e = blockIdx.x * 256 + threadIdx.x;
    if (e < N_EDGES) atomicAdd(&counts[eidx[N_EDGES + e]], 1);
}

__global__ __launch_bounds__(1024) void scan_kernel(const int* __restrict__ counts,
                                                    int* __restrict__ offsets,
                                                    int* __restrict__ cursor) {
    constexpr int T = 1024;
    constexpr int CHUNK = (N_NODES + T - 1) / T;  // 49
    const int tid = threadIdx.x;
    const int base = tid * CHUNK;

    int s = 0;
    #pragma unroll
    for (int i = 0; i < CHUNK; ++i) {
        int idx = base + i;
        if (idx < N_NODES) s += counts[idx];
    }
    __shared__ int sm[T];
    sm[tid] = s;
    __syncthreads();
    for (int off = 1; off < T; off <<= 1) {
        int v = (tid >= off) ? sm[tid - off] : 0;
        __syncthreads();
        sm[tid] += v;
        __syncthreads();
    }
    int run = sm[tid] - s;
    #pragma unroll
    for (int i = 0; i < CHUNK; ++i) {
        int idx = base + i;
        if (idx < N_NODES) {
            offsets[idx] = run;
            cursor[idx] = run;
            run += counts[idx];
        }
    }
    if (tid == T - 1) offsets[N_NODES] = sm[T - 1];
}

// slot[e] = CSR position of edge e (msgs written directly in dst-sorted order)
__global__ __launch_bounds__(256) void fill_slot(const int* __restrict__ eidx,
                                                 int* __restrict__ cursor,
                                                 int* __restrict__ slot) {
    int e = blockIdx.x * 256 + threadIdx.x;
    if (e < N_EDGES)
        slot[e] = atomicAdd(&cursor[eidx[N_EDGES + e]], 1);
}

// ---------------- per-node precompute: a1|a2|a3 (bf16, 128 per node) --------
// a1 = nf @ We1[0:128]   (32)   [src contribution, layer 1]
// a2 = nf @ We1[128:256] (32)   [dst contribution, layer 1]
// a3 = nf @ Wn1[0:128]   (64)   [dst contribution, layer 3]
__global__ __launch_bounds__(256) void node_pre(
    const float* __restrict__ nf,
    const float* __restrict__ We1, const float* __restrict__ Wn1,
    __hip_bfloat16* __restrict__ pre)
{
    __shared__ float xs[2][ND];
    const int node0 = blockIdx.x * 2;
    const int local = threadIdx.x >> 7;   // 0..1
    const int j = threadIdx.x & 127;
    xs[local][j] = nf[(size_t)(node0 + local) * ND + j];
    __syncthreads();
    const float* x = xs[local];

    const float* wp;
    int stride;
    if (j < 32)      { wp = We1 + j;               stride = H1; }
    else if (j < 64) { wp = We1 + ND * H1 + (j - 32); stride = H1; }
    else             { wp = Wn1 + (j - 64);        stride = H2; }

    float s = 0.0f;
    #pragma unroll 4
    for (int k = 0; k < ND; ++k) { s = fmaf(x[k], wp[0], s); wp += stride; }
    pre[(size_t)(node0 + local) * 128 + j] = __float2bfloat16(s);
}

// ---------------- Phase A: fused per-edge MLP -> bf16 msg rows (CSR order) --
__global__ __launch_bounds__(256, 2) void edge_mlp2(
    const float* __restrict__ ef, const int* __restrict__ eidx,
    const __hip_bfloat16* __restrict__ pre, const int* __restrict__ slot,
    const float* __restrict__ We1, const float* __restrict__ be1,
    const float* __restrict__ We2, const float* __restrict__ be2,
    const float* __restrict__ Wn1, const float* __restrict__ bn1,
    const float* __restrict__ Wn2, const float* __restrict__ bn2,
    unsigned* __restrict__ msgs)
{
    const int e = blockIdx.x * 256 + threadIdx.x;
    if (e >= N_EDGES) return;
    const int src = eidx[e];
    const int dst = eidx[N_EDGES + e];

    // gather precomputed rows: a1[src] (32 bf16), a2|a3[dst] (96 bf16)
    const uint4* pa = reinterpret_cast<const uint4*>(pre + (size_t)src * 128);
    const uint4* pd = reinterpret_cast<const uint4*>(pre + (size_t)dst * 128 + 32);
    uint4 qa[4], qd[12];
    #pragma unroll
    for (int i = 0; i < 4; ++i) qa[i] = pa[i];
    #pragma unroll
    for (int i = 0; i < 12; ++i) qd[i] = pd[i];

    // h2 init from a3 (free qd tail early)
    float h2[H2];
    {
        const unsigned* ud = reinterpret_cast<const unsigned*>(qd) + 16;
        #pragma unroll
        for (int i = 0; i < 32; ++i) {
            h2[2 * i]     = bn1[2 * i]     + bflo(ud[i]);
            h2[2 * i + 1] = bn1[2 * i + 1] + bfhi(ud[i]);
        }
    }

    // layer 1: h = relu(a1 + a2 + be1 + ef @ We1[256:320])
    float h[H1];
    {
        const unsigned* ua = reinterpret_cast<const unsigned*>(qa);
        const unsigned* ud = reinterpret_cast<const unsigned*>(qd);
        #pragma unroll
        for (int i = 0; i < 16; ++i) {
            h[2 * i]     = be1[2 * i]     + bflo(ua[i]) + bflo(ud[i]);
            h[2 * i + 1] = be1[2 * i + 1] + bfhi(ua[i]) + bfhi(ud[i]);
        }
    }
    const float4* egf = reinterpret_cast<const float4*>(ef) + e * (ED / 4);
    #pragma unroll 2
    for (int k4 = 0; k4 < ED / 4; ++k4) {
        float4 v = egf[k4];
        float xsv[4] = {v.x, v.y, v.z, v.w};
        #pragma unroll
        for (int c = 0; c < 4; ++c) {
            const float* w = We1 + (2 * ND + k4 * 4 + c) * H1;
            #pragma unroll
            for (int j = 0; j < H1; ++j) h[j] = fmaf(xsv[c], w[j], h[j]);
        }
    }
    #pragma unroll
    for (int j = 0; j < H1; ++j) h[j] = fmaxf(h[j], 0.0f);

    // layers 2+3 fused, k chunked by 32 so We2 row reads are contiguous bursts
    #pragma unroll 1
    for (int kc = 0; kc < MD; kc += 32) {
        float m[32];
        #pragma unroll
        for (int i = 0; i < 32; ++i) m[i] = be2[kc + i];
        #pragma unroll 4
        for (int t = 0; t < H1; ++t) {
            const float hv = h[t];
            const float* w = We2 + t * MD + kc;
            #pragma unroll
            for (int i = 0; i < 32; ++i) m[i] = fmaf(hv, w[i], m[i]);
        }
        #pragma unroll 2
        for (int i = 0; i < 32; ++i) {
            const float mv = fmaxf(m[i], 0.0f);
            const float* w = Wn1 + (ND + kc + i) * H2;
            #pragma unroll
            for (int j = 0; j < H2; ++j) h2[j] = fmaf(mv, w[j], h2[j]);
        }
    }
    #pragma unroll
    for (int j = 0; j < H2; ++j) h2[j] = fmaxf(h2[j], 0.0f);

    // layer 4: msg = relu(h2 @ Wn2 + bn2) -> bf16 row at CSR slot
    uint4* mrow = reinterpret_cast<uint4*>(msgs) + (size_t)slot[e] * (MD / 8);
    #pragma unroll 1
    for (int jo0 = 0; jo0 < MD; jo0 += 8) {
        float m[8];
        #pragma unroll
        for (int i = 0; i < 8; ++i) m[i] = bn2[jo0 + i];
        #pragma unroll
        for (int t = 0; t < H2; ++t) {
            const float hv = h2[t];
            const float* w = Wn2 + t * MD + jo0;
            #pragma unroll
            for (int i = 0; i < 8; ++i) m[i] = fmaf(hv, w[i], m[i]);
        }
        uint4 p;
        p.x = pack2bf(fmaxf(m[0], 0.f), fmaxf(m[1], 0.f));
        p.y = pack2bf(fmaxf(m[2], 0.f), fmaxf(m[3], 0.f));
        p.z = pack2bf(fmaxf(m[4], 0.f), fmaxf(m[5], 0.f));
        p.w = pack2bf(fmaxf(m[6], 0.f), fmaxf(m[7], 0.f));
        mrow[jo0 / 8] = p;
    }
}

// ---------------- Phase B: per-node streaming sum (msgs already CSR-sorted) -
__global__ __launch_bounds__(256) void gather2(
    const float* __restrict__ nf,
    const unsigned* __restrict__ msgs,
    const int* __restrict__ offsets,
    float* __restrict__ out)
{
    const int node = blockIdx.x * 4 + (threadIdx.x >> 6);
    const int lane = threadIdx.x & 63;

    float2 a = reinterpret_cast<const float2*>(nf)[node * (ND / 2) + lane];
    const int beg = offsets[node];
    const int end = offsets[node + 1];
    const unsigned* p = msgs + (size_t)beg * (MD / 2) + lane;
    for (int i = beg; i < end; ++i, p += MD / 2) {
        unsigned u = *p;
        a.x += bflo(u);
        a.y += bfhi(u);
    }
    reinterpret_cast<float2*>(out)[node * (ND / 2) + lane] = a;
}

extern "C" void kernel_launch(void* const* d_in, const int* in_sizes, int n_in,
                              void* d_out, int out_size, void* d_ws, size_t ws_size,
                              hipStream_t stream) {
    const float* nf  = (const float*)d_in[0];
    const float* ef  = (const float*)d_in[1];
    const int*  eidx = (const int*)d_in[2];
    const float* We1 = (const float*)d_in[3];
    const float* be1 = (const float*)d_in[4];
    const float* We2 = (const float*)d_in[5];
    const float* be2 = (const float*)d_in[6];
    const float* Wn1 = (const float*)d_in[7];
    const float* bn1 = (const float*)d_in[8];
    const float* Wn2 = (const float*)d_in[9];
    const float* bn2 = (const float*)d_in[10];
    float* out = (float*)d_out;

    char* ws = (char*)d_ws;
    unsigned* msgs        = (unsigned*)(ws + WS_MSGS);
    int* slot             = (int*)(ws + WS_SLOT);
    __hip_bfloat16* pre   = (__hip_bfloat16*)(ws + WS_PRE);
    int* counts           = (int*)(ws + WS_COUNTS);
    int* offsets          = (int*)(ws + WS_OFFSETS);
    int* cursor           = (int*)(ws + WS_CURSOR);
    (void)ws_size; (void)WS_NEEDED;

    // CSR build (int atomics only)
    hipMemsetAsync(counts, 0, (size_t)N_NODES * 4, stream);
    hist_kernel<<<(N_EDGES + 255) / 256, 256, 0, stream>>>(eidx, counts);
    scan_kernel<<<1, 1024, 0, stream>>>(counts, offsets, cursor);
    fill_slot<<<(N_EDGES + 255) / 256, 256, 0, stream>>>(eidx, cursor, slot);

    // per-node linear precompute (a1|a2|a3, bf16)
    node_pre<<<N_NODES / 2, 256, 0, stream>>>(nf, We1, Wn1, pre);

    // Phase A: per-edge MLP -> bf16 msg rows in CSR order
    edge_mlp2<<<(N_EDGES + 255) / 256, 256, 0, stream>>>(
        ef, eidx, pre, slot, We1, be1, We2, be2, Wn1, bn1, Wn2, bn2, msgs);

    // Phase B: per-node contiguous gather-sum
    gather2<<<N_NODES / 4, 256, 0, stream>>>(nf, msgs, offsets, out);
}

// Round 4
// 534.751 us; speedup vs baseline: 8.4188x; 2.2608x over previous
//
#include <hip/hip_runtime.h>
#include <hip/hip_bf16.h>

// Problem constants (from reference)
constexpr int N_NODES = 50000;
constexpr int N_EDGES = 600000;
constexpr int ND = 128;   // NODE_DIM
constexpr int ED = 64;    // EDGE_DIM
constexpr int MD = 128;   // MSG_DIM
constexpr int H1 = 32;    // edge MLP hidden
constexpr int H2 = 64;    // node MLP hidden

typedef __attribute__((ext_vector_type(8))) short short8;   // 8 bf16 (4 VGPRs)
typedef __attribute__((ext_vector_type(4))) float f32x4;    // MFMA acc

#define MFMA16(a, b, c) __builtin_amdgcn_mfma_f32_16x16x32_bf16((a), (b), (c), 0, 0, 0)

// ---------------- workspace layout (bytes) ----------------
constexpr size_t WS_MSGS    = 0;                                        // E*128 bf16
constexpr size_t WS_PRE     = WS_MSGS + (size_t)N_EDGES * MD * 2;       // N*128 bf16 (a1|a2|a3)
constexpr size_t WS_POS     = WS_PRE + (size_t)N_NODES * 128 * 2;       // E int
constexpr size_t WS_COUNTS  = WS_POS + (size_t)N_EDGES * 4;             // N int
constexpr size_t WS_OFFSETS = WS_COUNTS + (size_t)N_NODES * 4;          // N+1 int
constexpr size_t WS_WFE     = ((WS_OFFSETS + (size_t)(N_NODES + 1) * 4 + 15) / 16) * 16;
constexpr size_t WS_WFN     = WS_WFE + (size_t)44 * 64 * 16;            // 44 edge frags
constexpr size_t WS_END     = WS_WFN + (size_t)32 * 64 * 16;            // 32 node frags

__device__ inline float bflo(unsigned u) { return __uint_as_float(u << 16); }
__device__ inline float bfhi(unsigned u) { return __uint_as_float(u & 0xffff0000u); }
__device__ inline float bf2f(unsigned short v) { return __uint_as_float((unsigned)v << 16); }
__device__ inline short f2bf(float f) {
    __hip_bfloat16 h = __float2bfloat16(f);
    return *reinterpret_cast<short*>(&h);
}

// ---------------- weight fragment prep (once, tiny) ----------------
// B-fragment layout for mfma_f32_16x16x32_bf16: lane holds B[k=quad*8+j][n=lane&15],
// j=0..7 contiguous -> one short8 (16B) per (frag, lane).
// wfE frag ids: We1e(edge rows of We1)=0..3 (kt*2+nt), We2=4..11 (nt),
//               Wn1b(msg rows of Wn1)=12..27 (kt*4+nt), Wn2=28..43 (kt*8+nt).
// wfN frag ids: combined 128x128 B = [We1[0:128] | We1[128:256] | Wn1[0:128]] -> kt*8+nt.
__global__ __launch_bounds__(256) void wprep(
    const float* __restrict__ We1, const float* __restrict__ We2,
    const float* __restrict__ Wn1, const float* __restrict__ Wn2,
    short8* __restrict__ wfE, short8* __restrict__ wfN)
{
    const int g = blockIdx.x * 256 + threadIdx.x;   // 0..4863
    const int lane = g & 63;
    const int f = g >> 6;                            // 0..75
    const int m16 = lane & 15, quad = lane >> 4;
    short v[8];
    if (f < 44) {
        #pragma unroll
        for (int j = 0; j < 8; ++j) {
            const int kq = quad * 8 + j;
            float s;
            if (f < 4) {
                const int kt = f >> 1, nt = f & 1;
                s = We1[(size_t)(2 * ND + kt * 32 + kq) * H1 + nt * 16 + m16];
            } else if (f < 12) {
                const int nt = f - 4;
                s = We2[(size_t)kq * MD + nt * 16 + m16];
            } else if (f < 28) {
                const int ff = f - 12, kt = ff >> 2, nt = ff & 3;
                s = Wn1[(size_t)(ND + kt * 32 + kq) * H2 + nt * 16 + m16];
            } else {
                const int ff = f - 28, kt = ff >> 3, nt = ff & 7;
                s = Wn2[(size_t)(kt * 32 + kq) * MD + nt * 16 + m16];
            }
            v[j] = f2bf(s);
        }
        wfE[g] = short8{v[0], v[1], v[2], v[3], v[4], v[5], v[6], v[7]};
    } else {
        const int ff = f - 44, kt = ff >> 3, nt = ff & 7;
        const int n = nt * 16 + m16;
        #pragma unroll
        for (int j = 0; j < 8; ++j) {
            const int k = kt * 32 + quad * 8 + j;
            float s;
            if (n < 32)      s = We1[(size_t)k * H1 + n];
            else if (n < 64) s = We1[(size_t)(ND + k) * H1 + (n - 32)];
            else             s = Wn1[(size_t)k * H2 + (n - 64)];
            v[j] = f2bf(s);
        }
        wfN[(size_t)(f - 44) * 64 + lane] = short8{v[0], v[1], v[2], v[3], v[4], v[5], v[6], v[7]};
    }
}

// ---------------- CSR: histogram + within-segment position -----------------
__global__ __launch_bounds__(256) void hist_pos(const int* __restrict__ eidx,
                                                int* __restrict__ counts,
                                                int* __restrict__ pos) {
    const int e = blockIdx.x * 256 + threadIdx.x;
    if (e < N_EDGES) pos[e] = atomicAdd(&counts[eidx[N_EDGES + e]], 1);
}

__global__ __launch_bounds__(1024) void scan_kernel(const int* __restrict__ counts,
                                                    int* __restrict__ offsets) {
    constexpr int T = 1024;
    constexpr int CHUNK = (N_NODES + T - 1) / T;  // 49
    const int tid = threadIdx.x;
    const int base = tid * CHUNK;
    int s = 0;
    #pragma unroll
    for (int i = 0; i < CHUNK; ++i) {
        const int idx = base + i;
        if (idx < N_NODES) s += counts[idx];
    }
    __shared__ int sm[T];
    sm[tid] = s;
    __syncthreads();
    for (int off = 1; off < T; off <<= 1) {
        const int v = (tid >= off) ? sm[tid - off] : 0;
        __syncthreads();
        sm[tid] += v;
        __syncthreads();
    }
    int run = sm[tid] - s;
    #pragma unroll
    for (int i = 0; i < CHUNK; ++i) {
        const int idx = base + i;
        if (idx < N_NODES) {
            offsets[idx] = run;
            run += counts[idx];
        }
    }
    if (tid == T - 1) offsets[N_NODES] = sm[T - 1];
}

// ---------------- node precompute as MFMA GEMM: pre = nf @ [B128x128] -------
__global__ __launch_bounds__(256) void node_pre_mfma(
    const float* __restrict__ nf, const short8* __restrict__ wfN,
    unsigned short* __restrict__ pre)
{
    __shared__ short ost[4][2048];   // per-wave 16x128 out stage
    const int tid = threadIdx.x;
    const int w = tid >> 6, lane = tid & 63;
    const int m16 = lane & 15, quad = lane >> 4;
    const int n0 = blockIdx.x * 64 + w * 16;

    short8 a[4];
    #pragma unroll
    for (int kt = 0; kt < 4; ++kt) {
        const int node = min(n0 + m16, N_NODES - 1);
        const float* pn = nf + (size_t)node * ND + kt * 32 + quad * 8;
        const float4 f0 = *(const float4*)pn;
        const float4 f1 = *(const float4*)(pn + 4);
        a[kt] = short8{f2bf(f0.x), f2bf(f0.y), f2bf(f0.z), f2bf(f0.w),
                       f2bf(f1.x), f2bf(f1.y), f2bf(f1.z), f2bf(f1.w)};
    }
    f32x4 acc[8];
    #pragma unroll
    for (int nt = 0; nt < 8; ++nt) acc[nt] = f32x4{0.f, 0.f, 0.f, 0.f};
    #pragma unroll
    for (int kt = 0; kt < 4; ++kt) {
        #pragma unroll
        for (int nt = 0; nt < 8; ++nt)
            acc[nt] = MFMA16(a[kt], wfN[(size_t)(kt * 8 + nt) * 64 + lane], acc[nt]);
    }
    short* o = &ost[w][0];
    #pragma unroll
    for (int nt = 0; nt < 8; ++nt)
        #pragma unroll
        for (int r = 0; r < 4; ++r)
            o[(quad * 4 + r) * 128 + nt * 16 + m16] = f2bf(acc[nt][r]);  // no relu
    asm volatile("s_waitcnt lgkmcnt(0)" ::: "memory");
    #pragma unroll
    for (int i = 0; i < 4; ++i) {
        const int row = i * 4 + quad;
        const int node = n0 + row;
        if (node < N_NODES) {
            const uint4 v = ((const uint4*)(o + row * 128))[m16];
            *((uint4*)(pre + (size_t)node * 128) + m16) = v;
        }
    }
}

// ---------------- fused 4-layer edge MLP, full MFMA -------------------------
// 64 edges/block, 4 waves x 16-edge tiles. msgs written at CSR slot.
__global__ __launch_bounds__(256) void edge_mfma(
    const float* __restrict__ ef, const int* __restrict__ eidx,
    const unsigned short* __restrict__ pre,
    const int* __restrict__ pos, const int* __restrict__ offsets,
    const short8* __restrict__ wfE,
    const float* __restrict__ be1, const float* __restrict__ be2,
    const float* __restrict__ bn1, const float* __restrict__ bn2,
    unsigned short* __restrict__ msgs)
{
    constexpr int TE = 64;
    __shared__ float l1init[TE][36];            // a1[src]+a2[dst]+be1 (fp32, padded)
    __shared__ unsigned short a3lds[TE][72];    // a3[dst] bf16 (padded)
    __shared__ int slotlds[TE];
    __shared__ short wbufA[4][1152];            // albuf(stride 40) / h2buf(stride 72)
    __shared__ short wbufB[4][2176];            // msgbuf(stride 136) / outstage(stride 128)

    const int tid = threadIdx.x;
    const int e0 = blockIdx.x * TE;

    // ---- cooperative gather: 4 threads per edge ----
    {
        const int et = tid >> 2, p = tid & 3;
        const int e = e0 + et;                  // grid exact: e < N_EDGES
        const int src = eidx[e];
        const int dst = eidx[N_EDGES + e];
        if (p < 2) {
            const uint4* pa = (const uint4*)(pre + (size_t)src * 128);        // a1
            const uint4* pd = (const uint4*)(pre + (size_t)dst * 128 + 32);   // a2
            const float4* pb = (const float4*)be1;
            float4* o = (float4*)&l1init[et][p * 16];
            #pragma unroll
            for (int hx = 0; hx < 2; ++hx) {
                const uint4 ua = pa[p * 2 + hx];
                const uint4 ud = pd[p * 2 + hx];
                const float4 b0 = pb[p * 4 + hx * 2];
                const float4 b1 = pb[p * 4 + hx * 2 + 1];
                float4 r0, r1;
                r0.x = bflo(ua.x) + bflo(ud.x) + b0.x;
                r0.y = bfhi(ua.x) + bfhi(ud.x) + b0.y;
                r0.z = bflo(ua.y) + bflo(ud.y) + b0.z;
                r0.w = bfhi(ua.y) + bfhi(ud.y) + b0.w;
                r1.x = bflo(ua.z) + bflo(ud.z) + b1.x;
                r1.y = bfhi(ua.z) + bfhi(ud.z) + b1.y;
                r1.z = bflo(ua.w) + bflo(ud.w) + b1.z;
                r1.w = bfhi(ua.w) + bfhi(ud.w) + b1.w;
                o[hx * 2] = r0;
                o[hx * 2 + 1] = r1;
            }
        } else {
            const uint4* ps = (const uint4*)(pre + (size_t)dst * 128 + 64);   // a3
            uint4* oa = (uint4*)&a3lds[et][0];
            #pragma unroll
            for (int i = 0; i < 4; ++i) oa[(p - 2) * 4 + i] = ps[(p - 2) * 4 + i];
            if (p == 3) slotlds[et] = offsets[dst] + pos[e];
        }
    }
    __syncthreads();

    const int w = tid >> 6, lane = tid & 63;
    const int m16 = lane & 15, quad = lane >> 4;
    const int er0 = w * 16;
    short* alb = &wbufA[w][0];
    short* msb = &wbufB[w][0];

    // ef A-fragments straight from global (A[m=lane&15][k=quad*8+j])
    short8 aef[2];
    #pragma unroll
    for (int kt = 0; kt < 2; ++kt) {
        const size_t eb = (size_t)(e0 + er0 + m16) * ED + kt * 32 + quad * 8;
        const float4 f0 = *(const float4*)(ef + eb);
        const float4 f1 = *(const float4*)(ef + eb + 4);
        aef[kt] = short8{f2bf(f0.x), f2bf(f0.y), f2bf(f0.z), f2bf(f0.w),
                         f2bf(f1.x), f2bf(f1.y), f2bf(f1.z), f2bf(f1.w)};
    }

    // ---- L1: h(16x32) = relu(l1init + ef @ We1e) ----
    #pragma unroll
    for (int nt = 0; nt < 2; ++nt) {
        f32x4 acc;
        #pragma unroll
        for (int r = 0; r < 4; ++r)
            acc[r] = l1init[er0 + quad * 4 + r][nt * 16 + m16];
        acc = MFMA16(aef[0], wfE[(size_t)(0 * 2 + nt) * 64 + lane], acc);
        acc = MFMA16(aef[1], wfE[(size_t)(1 * 2 + nt) * 64 + lane], acc);
        #pragma unroll
        for (int r = 0; r < 4; ++r)
            alb[(quad * 4 + r) * 40 + nt * 16 + m16] = f2bf(fmaxf(acc[r], 0.0f));
    }
    asm volatile("s_waitcnt lgkmcnt(0)" ::: "memory");

    // ---- L2: msg(16x128) = relu(h @ We2 + be2) ----
    const short8 ah = *(const short8*)(alb + m16 * 40 + quad * 8);
    #pragma unroll
    for (int nt = 0; nt < 8; ++nt) {
        const float bb = be2[nt * 16 + m16];
        f32x4 acc = f32x4{bb, bb, bb, bb};
        acc = MFMA16(ah, wfE[(size_t)(4 + nt) * 64 + lane], acc);
        #pragma unroll
        for (int r = 0; r < 4; ++r)
            msb[(quad * 4 + r) * 136 + nt * 16 + m16] = f2bf(fmaxf(acc[r], 0.0f));
    }
    asm volatile("s_waitcnt lgkmcnt(0)" ::: "memory");

    // ---- L3: h2(16x64) = relu(a3 + bn1 + msg @ Wn1b) ----
    short8 am[4];
    #pragma unroll
    for (int kt = 0; kt < 4; ++kt)
        am[kt] = *(const short8*)(msb + m16 * 136 + kt * 32 + quad * 8);
    f32x4 acc3[4];
    #pragma unroll
    for (int nt = 0; nt < 4; ++nt) {
        const float bb = bn1[nt * 16 + m16];
        #pragma unroll
        for (int r = 0; r < 4; ++r)
            acc3[nt][r] = bb + bf2f(a3lds[er0 + quad * 4 + r][nt * 16 + m16]);
    }
    #pragma unroll
    for (int kt = 0; kt < 4; ++kt) {
        #pragma unroll
        for (int nt = 0; nt < 4; ++nt)
            acc3[nt] = MFMA16(am[kt], wfE[(size_t)(12 + kt * 4 + nt) * 64 + lane], acc3[nt]);
    }
    #pragma unroll
    for (int nt = 0; nt < 4; ++nt)
        #pragma unroll
        for (int r = 0; r < 4; ++r)
            alb[(quad * 4 + r) * 72 + nt * 16 + m16] = f2bf(fmaxf(acc3[nt][r], 0.0f));
    asm volatile("s_waitcnt lgkmcnt(0)" ::: "memory");

    // ---- L4: out(16x128) = relu(h2 @ Wn2 + bn2) ----
    short8 a4[2];
    #pragma unroll
    for (int kt = 0; kt < 2; ++kt)
        a4[kt] = *(const short8*)(alb + m16 * 72 + kt * 32 + quad * 8);
    f32x4 acc4[8];
    #pragma unroll
    for (int nt = 0; nt < 8; ++nt) {
        const float bb = bn2[nt * 16 + m16];
        acc4[nt] = f32x4{bb, bb, bb, bb};
    }
    #pragma unroll
    for (int kt = 0; kt < 2; ++kt) {
        #pragma unroll
        for (int nt = 0; nt < 8; ++nt)
            acc4[nt] = MFMA16(a4[kt], wfE[(size_t)(28 + kt * 8 + nt) * 64 + lane], acc4[nt]);
    }
    #pragma unroll
    for (int nt = 0; nt < 8; ++nt)
        #pragma unroll
        for (int r = 0; r < 4; ++r)
            msb[(quad * 4 + r) * 128 + nt * 16 + m16] = f2bf(fmaxf(acc4[nt][r], 0.0f));
    asm volatile("s_waitcnt lgkmcnt(0)" ::: "memory");

    // ---- coalesced row store to msgs[slot] (quarter-wave per 256B row) ----
    #pragma unroll
    for (int i = 0; i < 4; ++i) {
        const int row = i * 4 + quad;
        const int sl = slotlds[er0 + row];
        const uint4 v = ((const uint4*)(msb + row * 128))[m16];
        *((uint4*)(msgs + (size_t)sl * 128) + m16) = v;
    }
}

// ---------------- Phase B: per-node streaming sum (msgs CSR-sorted) ---------
__global__ __launch_bounds__(256) void gather2(
    const float* __restrict__ nf,
    const unsigned* __restrict__ msgs,
    const int* __restrict__ offsets,
    float* __restrict__ out)
{
    const int node = blockIdx.x * 4 + (threadIdx.x >> 6);
    const int lane = threadIdx.x & 63;

    float2 a = reinterpret_cast<const float2*>(nf)[node * (ND / 2) + lane];
    const int beg = offsets[node];
    const int end = offsets[node + 1];
    const unsigned* p = msgs + (size_t)beg * (MD / 2) + lane;
    for (int i = beg; i < end; ++i, p += MD / 2) {
        const unsigned u = *p;
        a.x += bflo(u);
        a.y += bfhi(u);
    }
    reinterpret_cast<float2*>(out)[node * (ND / 2) + lane] = a;
}

extern "C" void kernel_launch(void* const* d_in, const int* in_sizes, int n_in,
                              void* d_out, int out_size, void* d_ws, size_t ws_size,
                              hipStream_t stream) {
    const float* nf  = (const float*)d_in[0];
    const float* ef  = (const float*)d_in[1];
    const int*  eidx = (const int*)d_in[2];
    const float* We1 = (const float*)d_in[3];
    const float* be1 = (const float*)d_in[4];
    const float* We2 = (const float*)d_in[5];
    const float* be2 = (const float*)d_in[6];
    const float* Wn1 = (const float*)d_in[7];
    const float* bn1 = (const float*)d_in[8];
    const float* Wn2 = (const float*)d_in[9];
    const float* bn2 = (const float*)d_in[10];
    float* out = (float*)d_out;

    char* ws = (char*)d_ws;
    unsigned short* msgs = (unsigned short*)(ws + WS_MSGS);
    unsigned short* pre  = (unsigned short*)(ws + WS_PRE);
    int* pos             = (int*)(ws + WS_POS);
    int* counts          = (int*)(ws + WS_COUNTS);
    int* offsets         = (int*)(ws + WS_OFFSETS);
    short8* wfE          = (short8*)(ws + WS_WFE);
    short8* wfN          = (short8*)(ws + WS_WFN);
    (void)ws_size; (void)WS_END;

    hipMemsetAsync(counts, 0, (size_t)N_NODES * 4, stream);
    wprep<<<19, 256, 0, stream>>>(We1, We2, Wn1, Wn2, wfE, wfN);
    hist_pos<<<(N_EDGES + 255) / 256, 256, 0, stream>>>(eidx, counts, pos);
    scan_kernel<<<1, 1024, 0, stream>>>(counts, offsets);
    node_pre_mfma<<<(N_NODES + 63) / 64, 256, 0, stream>>>(nf, wfN, pre);
    edge_mfma<<<N_EDGES / 64, 256, 0, stream>>>(
        ef, eidx, pre, pos, offsets, wfE, be1, be2, bn1, bn2, msgs);
    gather2<<<N_NODES / 4, 256, 0, stream>>>(nf, (const unsigned*)msgs, offsets, out);
}